// Round 1
// baseline (138.809 us; speedup 1.0000x reference)
//
#include <hip/hip_runtime.h>
#include <hip/hip_bf16.h>

#define NB 16384
#define ND 1024
#define NT 20
#define NC 100

// GEMM tiling
#define TILE_M 64
#define N_PAD 112               // 7 x 16 frags, covers C=100 (cols 100..111 zero)
#define KS 64                   // K step
#define A_BYTES (TILE_M * KS * 2)   // 8192
#define B_BYTES (N_PAD * KS * 2)    // 14336
#define BUF_BYTES (A_BYTES + B_BYTES)
#define MAX_TILES 256           // worst case: all B samples in one task

typedef __bf16  bf16x8 __attribute__((ext_vector_type(8)));
typedef float   f32x4  __attribute__((ext_vector_type(4)));

__device__ __forceinline__ unsigned int f2bf(float f) {
    unsigned int u = __builtin_bit_cast(unsigned int, f);
    u += 0x7FFFu + ((u >> 16) & 1u);   // round-to-nearest-even
    return u >> 16;
}
__device__ __forceinline__ unsigned long long pack4(float a, float b, float c, float d) {
    return (unsigned long long)f2bf(a)
         | ((unsigned long long)f2bf(b) << 16)
         | ((unsigned long long)f2bf(c) << 32)
         | ((unsigned long long)f2bf(d) << 48);
}

// ---------------- bucketing ----------------

__global__ void count_kernel(const int* __restrict__ t, int* __restrict__ counts) {
    __shared__ int h[NT];
    int tid = threadIdx.x;
    if (tid < NT) h[tid] = 0;
    __syncthreads();
    int i = blockIdx.x * 256 + tid;
    atomicAdd(&h[t[i]], 1);
    __syncthreads();
    if (tid < NT && h[tid] > 0) atomicAdd(&counts[tid], h[tid]);
}

__global__ void scan_kernel(const int* __restrict__ counts,
                            int* __restrict__ offsets, int* __restrict__ cursors) {
    if (threadIdx.x == 0) {
        int acc = 0;
        for (int i = 0; i < NT; ++i) {
            offsets[i] = acc; cursors[i] = acc; acc += counts[i];
        }
        offsets[NT] = acc;
    }
}

__global__ void scatter_kernel(const int* __restrict__ t, int* __restrict__ cursors,
                               int* __restrict__ idx_list) {
    __shared__ int h[NT];
    __shared__ int base[NT];
    int tid = threadIdx.x;
    if (tid < NT) h[tid] = 0;
    __syncthreads();
    int i = blockIdx.x * 256 + tid;
    int task = t[i];
    int lpos = atomicAdd(&h[task], 1);
    __syncthreads();
    if (tid < NT && h[tid] > 0) base[tid] = atomicAdd(&cursors[tid], h[tid]);
    __syncthreads();
    idx_list[base[task] + lpos] = i;
}

// ---------------- grouped GEMM ----------------
// Per task: pred[idx[j], c] = sum_k x[idx[j], k] * W[task, c, k] + b[task, c]
// Both operands K-contiguous -> NT GEMM, mfma_f32_16x16x32_bf16.
// A frag: lane holds row = l&15, k = 8*(l>>4)+j ; B frag: col = l&15, same k.
// C/D frag: col = l&15, row = (l>>4)*4 + reg  (m89-verified mapping).

__global__ __launch_bounds__(256) void gemm_kernel(
    const float* __restrict__ x, const float* __restrict__ W,
    const float* __restrict__ bias, const int* __restrict__ offsets,
    const int* __restrict__ idx_list, float* __restrict__ out)
{
    __shared__ __align__(16) char lds[2 * BUF_BYTES];
    const int bid  = blockIdx.x;
    const int task = bid >> 8;          // MAX_TILES == 256
    const int tile = bid & 255;
    const int seg  = offsets[task];
    const int cnt  = offsets[task + 1] - seg;
    const int m0   = tile * TILE_M;
    if (m0 >= cnt) return;

    const int tid  = threadIdx.x;
    const int wave = tid >> 6;
    const int lane = tid & 63;

    const float* Wt = W + (size_t)task * NC * ND;

    // staging descriptors: each thread loads 4 f32 per chunk, A = 4 chunks, B = 7 chunks
    const float* aP[4]; unsigned aO[4];
#pragma unroll
    for (int p = 0; p < 4; ++p) {
        int flat = p * 1024 + tid * 4;
        int row = flat >> 6, k = flat & 63;
        int sr = m0 + row;
        aP[p] = (sr < cnt) ? (x + (size_t)idx_list[seg + sr] * ND + k) : nullptr;
        aO[p] = (unsigned)(row * 128 + ((k * 2) ^ ((row & 7) << 4)));   // XOR swizzle
    }
    const float* bP[7]; unsigned bO[7];
#pragma unroll
    for (int p = 0; p < 7; ++p) {
        int flat = p * 1024 + tid * 4;
        int c = flat >> 6, k = flat & 63;
        bP[p] = (c < NC) ? (Wt + (size_t)c * ND + k) : nullptr;
        bO[p] = (unsigned)(A_BYTES + c * 128 + ((k * 2) ^ ((c & 7) << 4)));
    }

    float4 zf4 = make_float4(0.f, 0.f, 0.f, 0.f);
    float4 ar[4], br[7];

    auto loadRegs = [&](int k0) {
#pragma unroll
        for (int p = 0; p < 4; ++p)
            ar[p] = aP[p] ? *(const float4*)(aP[p] + k0) : zf4;
#pragma unroll
        for (int p = 0; p < 7; ++p)
            br[p] = bP[p] ? *(const float4*)(bP[p] + k0) : zf4;
    };
    auto cvtStore = [&](int buf) {
        char* wb = lds + buf * BUF_BYTES;
#pragma unroll
        for (int p = 0; p < 4; ++p)
            *(unsigned long long*)(wb + aO[p]) = pack4(ar[p].x, ar[p].y, ar[p].z, ar[p].w);
#pragma unroll
        for (int p = 0; p < 7; ++p)
            *(unsigned long long*)(wb + bO[p]) = pack4(br[p].x, br[p].y, br[p].z, br[p].w);
    };

    f32x4 acc[7] = {};
    const int rsel = lane & 15;
    const int kb   = (lane >> 4) * 8;
    const int rowA = wave * 16 + rsel;

    auto compute = [&](int buf) {
        const char* rb = lds + buf * BUF_BYTES;
#pragma unroll
        for (int kk = 0; kk < 2; ++kk) {
            int k2 = (kk * 32 + kb) * 2;
            bf16x8 a = *(const bf16x8*)(rb + rowA * 128 + (k2 ^ ((rowA & 7) << 4)));
#pragma unroll
            for (int n = 0; n < 7; ++n) {
                int c = n * 16 + rsel;
                bf16x8 bb = *(const bf16x8*)(rb + A_BYTES + c * 128 + (k2 ^ ((c & 7) << 4)));
                acc[n] = __builtin_amdgcn_mfma_f32_16x16x32_bf16(a, bb, acc[n], 0, 0, 0);
            }
        }
    };

    // prologue
    loadRegs(0);
    cvtStore(0);
    __syncthreads();

    int cur = 0;
#pragma unroll 1
    for (int s = 0; s < ND / KS; ++s) {
        if (s < ND / KS - 1) loadRegs((s + 1) * KS);   // issue next-tile global loads
        compute(cur);                                   // ds_read + MFMA on current
        if (s < ND / KS - 1) cvtStore(cur ^ 1);         // vmcnt-wait + convert + ds_write
        __syncthreads();
        cur ^= 1;
    }

    // epilogue: bias + scatter-store
    const int rgrp = (lane >> 4) * 4;
#pragma unroll
    for (int n = 0; n < 7; ++n) {
        int c = n * 16 + rsel;
        if (c < NC) {
            float bv = bias[task * NC + c];
#pragma unroll
            for (int r = 0; r < 4; ++r) {
                int gm = m0 + wave * 16 + rgrp + r;
                if (gm < cnt) {
                    int oi = idx_list[seg + gm];
                    out[(size_t)oi * NC + c] = acc[n][r] + bv;
                }
            }
        }
    }
}

// ---------------- launch ----------------

extern "C" void kernel_launch(void* const* d_in, const int* in_sizes, int n_in,
                              void* d_out, int out_size, void* d_ws, size_t ws_size,
                              hipStream_t stream) {
    const float* x    = (const float*)d_in[0];
    const int*   t    = (const int*)d_in[1];
    const float* W    = (const float*)d_in[2];
    const float* bias = (const float*)d_in[3];
    float* out = (float*)d_out;

    int* wsi      = (int*)d_ws;
    int* counts   = wsi;        // 20 ints
    int* offsets  = wsi + 32;   // 21 ints
    int* cursors  = wsi + 64;   // 20 ints
    int* idx_list = wsi + 96;   // NB ints

    hipMemsetAsync(counts, 0, 32 * sizeof(int), stream);
    count_kernel  <<<NB / 256, 256, 0, stream>>>(t, counts);
    scan_kernel   <<<1, 64, 0, stream>>>(counts, offsets, cursors);
    scatter_kernel<<<NB / 256, 256, 0, stream>>>(t, cursors, idx_list);
    gemm_kernel   <<<NT * MAX_TILES, 256, 0, stream>>>(x, W, bias, offsets, idx_list, out);
}

// Round 2
// 100.766 us; speedup vs baseline: 1.3775x; 1.3775x over previous
//
#include <hip/hip_runtime.h>
#include <hip/hip_bf16.h>

#define NB 16384
#define ND 1024
#define NT 20
#define NC 100

// GEMM tiling
#define TILE_M 64
#define N_PAD 112               // 7 x 16 frags, covers C=100 (cols 100..111 zero)
#define KS 64                   // K step
#define SPLIT 4                 // K split factor: each block does ND/SPLIT = 256
#define STEPS (ND / SPLIT / KS) // 4 K-steps per block
#define A_BYTES (TILE_M * KS * 2)   // 8192
#define B_BYTES (N_PAD * KS * 2)    // 14336
#define BUF_BYTES (A_BYTES + B_BYTES)
#define MTILES 16               // M-tile slots per task (overflow handled by in-block loop)

#define SCALE 4194304.0f        // 2^22 fixed-point scale for deterministic int accumulation
#define INV_SCALE (1.0f / 4194304.0f)

typedef __bf16  bf16x8 __attribute__((ext_vector_type(8)));
typedef float   f32x4  __attribute__((ext_vector_type(4)));

__device__ __forceinline__ unsigned int f2bf(float f) {
    unsigned int u = __builtin_bit_cast(unsigned int, f);
    u += 0x7FFFu + ((u >> 16) & 1u);   // round-to-nearest-even
    return u >> 16;
}
__device__ __forceinline__ unsigned long long pack4(float a, float b, float c, float d) {
    return (unsigned long long)f2bf(a)
         | ((unsigned long long)f2bf(b) << 16)
         | ((unsigned long long)f2bf(c) << 32)
         | ((unsigned long long)f2bf(d) << 48);
}

// ---------------- bucketing ----------------

__global__ void count_kernel(const int* __restrict__ t, int* __restrict__ counts) {
    __shared__ int h[NT];
    int tid = threadIdx.x;
    if (tid < NT) h[tid] = 0;
    __syncthreads();
    int i = blockIdx.x * 256 + tid;
    atomicAdd(&h[t[i]], 1);
    __syncthreads();
    if (tid < NT && h[tid] > 0) atomicAdd(&counts[tid], h[tid]);
}

__global__ void scan_kernel(const int* __restrict__ counts,
                            int* __restrict__ offsets, int* __restrict__ cursors) {
    if (threadIdx.x == 0) {
        int acc = 0;
        for (int i = 0; i < NT; ++i) {
            offsets[i] = acc; cursors[i] = acc; acc += counts[i];
        }
        offsets[NT] = acc;
    }
}

__global__ void scatter_kernel(const int* __restrict__ t, int* __restrict__ cursors,
                               int* __restrict__ idx_list) {
    __shared__ int h[NT];
    __shared__ int base[NT];
    int tid = threadIdx.x;
    if (tid < NT) h[tid] = 0;
    __syncthreads();
    int i = blockIdx.x * 256 + tid;
    int task = t[i];
    int lpos = atomicAdd(&h[task], 1);
    __syncthreads();
    if (tid < NT && h[tid] > 0) base[tid] = atomicAdd(&cursors[tid], h[tid]);
    __syncthreads();
    idx_list[base[task] + lpos] = i;
}

// ---------------- grouped GEMM, split-K ----------------
// Block (task, tile, kq): rows [tile*64, ...) of task's segment, K in
// [kq*256, kq*256+256). Accumulates fixed-point int partials into out
// (deterministic: integer adds are order-independent).

__global__ __launch_bounds__(256) void gemm_kernel(
    const float* __restrict__ x, const float* __restrict__ W,
    const int* __restrict__ offsets, const int* __restrict__ idx_list,
    int* __restrict__ outi)
{
    __shared__ __align__(16) char lds[2 * BUF_BYTES];
    const int bid  = blockIdx.x;
    const int task = bid / (MTILES * SPLIT);
    const int rem  = bid - task * (MTILES * SPLIT);
    const int kq   = rem >> 4;          // MTILES == 16
    const int tile = rem & (MTILES - 1);
    const int seg  = offsets[task];
    const int cnt  = offsets[task + 1] - seg;
    const int kbase = kq * (ND / SPLIT);

    const int tid  = threadIdx.x;
    const int wave = tid >> 6;
    const int lane = tid & 63;

    const float* Wt = W + (size_t)task * NC * ND;

    // B staging descriptors (invariant per block): 7 chunks of 4 f32/thread
    const float* bP[7]; unsigned bO[7];
#pragma unroll
    for (int p = 0; p < 7; ++p) {
        int flat = p * 1024 + tid * 4;
        int c = flat >> 6, k = flat & 63;
        bP[p] = (c < NC) ? (Wt + (size_t)c * ND + k) : nullptr;
        bO[p] = (unsigned)(A_BYTES + c * 128 + ((k * 2) ^ ((c & 7) << 4)));
    }
    // A LDS offsets (invariant); A pointers set per m0
    unsigned aO[4]; int aRow[4], aK[4];
#pragma unroll
    for (int p = 0; p < 4; ++p) {
        int flat = p * 1024 + tid * 4;
        aRow[p] = flat >> 6; aK[p] = flat & 63;
        aO[p] = (unsigned)(aRow[p] * 128 + ((aK[p] * 2) ^ ((aRow[p] & 7) << 4)));
    }

    const float4 zf4 = make_float4(0.f, 0.f, 0.f, 0.f);
    const int rsel = lane & 15;
    const int kb   = (lane >> 4) * 8;
    const int rowA = wave * 16 + rsel;
    const int rgrp = (lane >> 4) * 4;

    for (int m0 = tile * TILE_M; m0 < cnt; m0 += MTILES * TILE_M) {
        const float* aP[4];
#pragma unroll
        for (int p = 0; p < 4; ++p) {
            int sr = m0 + aRow[p];
            aP[p] = (sr < cnt) ? (x + (size_t)idx_list[seg + sr] * ND + aK[p]) : nullptr;
        }

        float4 ar[4], br[7];
        auto loadRegs = [&](int k0) {
#pragma unroll
            for (int p = 0; p < 4; ++p)
                ar[p] = aP[p] ? *(const float4*)(aP[p] + k0) : zf4;
#pragma unroll
            for (int p = 0; p < 7; ++p)
                br[p] = bP[p] ? *(const float4*)(bP[p] + k0) : zf4;
        };
        auto cvtStore = [&](int buf) {
            char* wb = lds + buf * BUF_BYTES;
#pragma unroll
            for (int p = 0; p < 4; ++p)
                *(unsigned long long*)(wb + aO[p]) = pack4(ar[p].x, ar[p].y, ar[p].z, ar[p].w);
#pragma unroll
            for (int p = 0; p < 7; ++p)
                *(unsigned long long*)(wb + bO[p]) = pack4(br[p].x, br[p].y, br[p].z, br[p].w);
        };

        f32x4 acc[7] = {};
        auto compute = [&](int buf) {
            const char* rb = lds + buf * BUF_BYTES;
#pragma unroll
            for (int kk = 0; kk < 2; ++kk) {
                int k2 = (kk * 32 + kb) * 2;
                bf16x8 a = *(const bf16x8*)(rb + rowA * 128 + (k2 ^ ((rowA & 7) << 4)));
#pragma unroll
                for (int n = 0; n < 7; ++n) {
                    int c = n * 16 + rsel;
                    bf16x8 bb = *(const bf16x8*)(rb + A_BYTES + c * 128 + (k2 ^ ((c & 7) << 4)));
                    acc[n] = __builtin_amdgcn_mfma_f32_16x16x32_bf16(a, bb, acc[n], 0, 0, 0);
                }
            }
        };

        loadRegs(kbase);
        cvtStore(0);
        __syncthreads();

        int cur = 0;
#pragma unroll 1
        for (int s = 0; s < STEPS; ++s) {
            if (s < STEPS - 1) loadRegs(kbase + (s + 1) * KS);
            compute(cur);
            if (s < STEPS - 1) cvtStore(cur ^ 1);
            __syncthreads();
            cur ^= 1;
        }

        // epilogue: fixed-point atomic accumulate (order-independent)
#pragma unroll
        for (int n = 0; n < 7; ++n) {
            int c = n * 16 + rsel;
            if (c < NC) {
#pragma unroll
                for (int r = 0; r < 4; ++r) {
                    int gm = m0 + wave * 16 + rgrp + r;
                    if (gm < cnt) {
                        int oi = idx_list[seg + gm];
                        atomicAdd(&outi[(size_t)oi * NC + c],
                                  __float2int_rn(acc[n][r] * SCALE));
                    }
                }
            }
        }
    }
}

// ---------------- finalize: int fixed-point -> float, + bias ----------------

__global__ void finalize_kernel(int* __restrict__ io, const int* __restrict__ t,
                                const float* __restrict__ bias) {
    int id = blockIdx.x * 256 + threadIdx.x;     // id < NB*NC
    int oi = id / NC;
    int c  = id - oi * NC;
    float v = (float)io[id] * INV_SCALE + bias[t[oi] * NC + c];
    ((float*)io)[id] = v;
}

// ---------------- launch ----------------

extern "C" void kernel_launch(void* const* d_in, const int* in_sizes, int n_in,
                              void* d_out, int out_size, void* d_ws, size_t ws_size,
                              hipStream_t stream) {
    const float* x    = (const float*)d_in[0];
    const int*   t    = (const int*)d_in[1];
    const float* W    = (const float*)d_in[2];
    const float* bias = (const float*)d_in[3];

    int* wsi      = (int*)d_ws;
    int* counts   = wsi;        // 20 ints
    int* offsets  = wsi + 32;   // 21 ints
    int* cursors  = wsi + 64;   // 20 ints
    int* idx_list = wsi + 96;   // NB ints

    hipMemsetAsync(counts, 0, 32 * sizeof(int), stream);
    hipMemsetAsync(d_out, 0, (size_t)NB * NC * sizeof(int), stream);
    count_kernel   <<<NB / 256, 256, 0, stream>>>(t, counts);
    scan_kernel    <<<1, 64, 0, stream>>>(counts, offsets, cursors);
    scatter_kernel <<<NB / 256, 256, 0, stream>>>(t, cursors, idx_list);
    gemm_kernel    <<<NT * MTILES * SPLIT, 256, 0, stream>>>(x, W, offsets, idx_list,
                                                             (int*)d_out);
    finalize_kernel<<<NB * NC / 256, 256, 0, stream>>>((int*)d_out, t, bias);
}

// Round 3
// 82.771 us; speedup vs baseline: 1.6770x; 1.2174x over previous
//
#include <hip/hip_runtime.h>
#include <hip/hip_bf16.h>

#define NB 16384
#define ND 1024
#define NT 20
#define NC 100

#define TILE_M 64
#define N_PAD 112               // 7 x 16 frags, covers C=100
#define KS 64                   // K per staged B tile
#define SPLIT 4                 // each block covers K=256
#define B_BYTES (N_PAD * KS * 2)    // 14336 bytes (bf16)
#define MTILES 16

#define SCALE 4194304.0f        // 2^22 fixed-point for deterministic accumulation
#define INV_SCALE (1.0f / 4194304.0f)

typedef __bf16  bf16x8 __attribute__((ext_vector_type(8)));
typedef float   f32x4  __attribute__((ext_vector_type(4)));

__device__ __forceinline__ unsigned int f2bf(float f) {
    unsigned int u = __builtin_bit_cast(unsigned int, f);
    u += 0x7FFFu + ((u >> 16) & 1u);   // round-to-nearest-even
    return u >> 16;
}
__device__ __forceinline__ unsigned long long pack4(float a, float b, float c, float d) {
    return (unsigned long long)f2bf(a)
         | ((unsigned long long)f2bf(b) << 16)
         | ((unsigned long long)f2bf(c) << 32)
         | ((unsigned long long)f2bf(d) << 48);
}
__device__ __forceinline__ bf16x8 mk_frag(float4 a, float4 b) {
    union { unsigned long long u[2]; bf16x8 v; } r;
    r.u[0] = pack4(a.x, a.y, a.z, a.w);
    r.u[1] = pack4(b.x, b.y, b.z, b.w);
    return r.v;
}

// ---------------- bucketing ----------------

__global__ void count_kernel(const int* __restrict__ t, int* __restrict__ counts) {
    __shared__ int h[NT];
    int tid = threadIdx.x;
    if (tid < NT) h[tid] = 0;
    __syncthreads();
    int i = blockIdx.x * 256 + tid;
    atomicAdd(&h[t[i]], 1);
    __syncthreads();
    if (tid < NT && h[tid] > 0) atomicAdd(&counts[tid], h[tid]);
}

__global__ void scan_kernel(const int* __restrict__ counts,
                            int* __restrict__ offsets, int* __restrict__ cursors) {
    if (threadIdx.x == 0) {
        int acc = 0;
        for (int i = 0; i < NT; ++i) {
            offsets[i] = acc; cursors[i] = acc; acc += counts[i];
        }
        offsets[NT] = acc;
    }
}

__global__ void scatter_kernel(const int* __restrict__ t, int* __restrict__ cursors,
                               int* __restrict__ idx_list) {
    __shared__ int h[NT];
    __shared__ int base[NT];
    int tid = threadIdx.x;
    if (tid < NT) h[tid] = 0;
    __syncthreads();
    int i = blockIdx.x * 256 + tid;
    int task = t[i];
    int lpos = atomicAdd(&h[task], 1);
    __syncthreads();
    if (tid < NT && h[tid] > 0) base[tid] = atomicAdd(&cursors[tid], h[tid]);
    __syncthreads();
    idx_list[base[task] + lpos] = i;
}

// ---------------- grouped GEMM, split-K, A-direct + B-LDS ----------------
// Block (task, tile, kq): 64 rows x 112 cols x K=256.
// A: global->reg bf16 frags (k-contiguous per lane). B: reg-staged to swizzled
// bf16 LDS, double-buffered, 2-deep register prefetch.

__global__ __launch_bounds__(256, 3) void gemm_kernel(
    const float* __restrict__ x, const float* __restrict__ W,
    const int* __restrict__ offsets, const int* __restrict__ idx_list,
    int* __restrict__ outi)
{
    __shared__ __align__(16) char lds[2 * B_BYTES];
    const int bid  = blockIdx.x;
    const int task = bid / (MTILES * SPLIT);
    const int rem  = bid - task * (MTILES * SPLIT);
    const int kq   = rem >> 4;          // MTILES == 16
    const int tile = rem & (MTILES - 1);
    const int seg  = offsets[task];
    const int cnt  = offsets[task + 1] - seg;
    const int kbase = kq * (ND / SPLIT);
    if (tile * TILE_M >= cnt) return;

    const int tid  = threadIdx.x;
    const int wave = tid >> 6;
    const int lane = tid & 63;
    const int rsel = lane & 15;
    const int kb   = (lane >> 4) * 8;

    const float* Wt = W + (size_t)task * NC * ND;

    // B staging mapping: col c = p*16 + (tid>>4), k = (tid&15)*4  (p = 0..6)
    const int bRow  = tid >> 4;         // 0..15
    const int bK4   = (tid & 15) * 4;
    const float* bBase = Wt + (size_t)bRow * ND + bK4 + kbase;
    const unsigned bOfs = (unsigned)(bRow * 128 + ((bK4 * 2) ^ ((bRow & 7) << 4)));
    const bool bOK6 = (96 + bRow) < NC;

    // compute-side LDS read base: col c = n*16 + rsel
    const unsigned rBase = (unsigned)(rsel * 128);
    const unsigned rSwz  = (unsigned)((rsel & 7) << 4);

    const float4 zf4 = make_float4(0.f, 0.f, 0.f, 0.f);

    const float* pA = nullptr;
    f32x4 acc[7];

    auto bload = [&](float4* R, int k0) {
#pragma unroll
        for (int p = 0; p < 7; ++p)
            R[p] = (p < 6 || bOK6) ? *(const float4*)(bBase + p * 16 * ND + k0) : zf4;
    };
    auto aload = [&](float4* R, int k0) {
        R[0] = *(const float4*)(pA + k0);
        R[1] = *(const float4*)(pA + k0 + 4);
        R[2] = *(const float4*)(pA + k0 + 32);
        R[3] = *(const float4*)(pA + k0 + 36);
    };
    auto bstore = [&](const float4* R, int buf) {
        char* wb = lds + buf * B_BYTES + bOfs;
#pragma unroll
        for (int p = 0; p < 7; ++p)
            *(unsigned long long*)(wb + p * 2048) = pack4(R[p].x, R[p].y, R[p].z, R[p].w);
    };
    auto compute = [&](int buf, bf16x8 a0, bf16x8 a1) {
        const char* rb = lds + buf * B_BYTES + rBase;
#pragma unroll
        for (int kk = 0; kk < 2; ++kk) {
            unsigned k2 = ((unsigned)((kk * 32 + kb) * 2)) ^ rSwz;
#pragma unroll
            for (int n = 0; n < 7; ++n) {
                bf16x8 bb = *(const bf16x8*)(rb + n * 2048 + k2);
                acc[n] = __builtin_amdgcn_mfma_f32_16x16x32_bf16(kk ? a1 : a0, bb, acc[n], 0, 0, 0);
            }
        }
    };

    for (int m0 = tile * TILE_M; m0 < cnt; m0 += MTILES * TILE_M) {
        int sr = m0 + wave * 16 + rsel;
        int arow = idx_list[seg + (sr < cnt ? sr : 0)];   // dummy row 0 for tail lanes
        pA = x + (size_t)arow * ND + kbase + kb;
#pragma unroll
        for (int n = 0; n < 7; ++n) acc[n] = (f32x4){0.f, 0.f, 0.f, 0.f};

        float4 br0[7], br1[7], ar0[4], ar1[4];

        // prologue: 2-deep issue
        bload(br0, 0);      aload(ar0, 0);
        bload(br1, KS);     aload(ar1, KS);
        __builtin_amdgcn_sched_barrier(0);
        bstore(br0, 0);
        __syncthreads();

        // s = 0
        bload(br0, 2 * KS);
        {
            bf16x8 a0 = mk_frag(ar0[0], ar0[1]);
            bf16x8 a1 = mk_frag(ar0[2], ar0[3]);
            aload(ar0, 2 * KS);
            __builtin_amdgcn_sched_barrier(0);
            compute(0, a0, a1);
        }
        bstore(br1, 1);
        __syncthreads();

        // s = 1
        bload(br1, 3 * KS);
        {
            bf16x8 a0 = mk_frag(ar1[0], ar1[1]);
            bf16x8 a1 = mk_frag(ar1[2], ar1[3]);
            aload(ar1, 3 * KS);
            __builtin_amdgcn_sched_barrier(0);
            compute(1, a0, a1);
        }
        bstore(br0, 0);
        __syncthreads();

        // s = 2
        {
            bf16x8 a0 = mk_frag(ar0[0], ar0[1]);
            bf16x8 a1 = mk_frag(ar0[2], ar0[3]);
            compute(0, a0, a1);
        }
        bstore(br1, 1);
        __syncthreads();

        // s = 3
        {
            bf16x8 a0 = mk_frag(ar1[0], ar1[1]);
            bf16x8 a1 = mk_frag(ar1[2], ar1[3]);
            compute(1, a0, a1);
        }

        // epilogue: fixed-point atomic accumulate (order-independent)
        const int rgrp = (lane >> 4) * 4;
#pragma unroll
        for (int n = 0; n < 7; ++n) {
            int c = n * 16 + rsel;
            if (c < NC) {
#pragma unroll
                for (int r = 0; r < 4; ++r) {
                    int gm = m0 + wave * 16 + rgrp + r;
                    if (gm < cnt) {
                        int oi = idx_list[seg + gm];
                        atomicAdd(&outi[(size_t)oi * NC + c],
                                  __float2int_rn(acc[n][r] * SCALE));
                    }
                }
            }
        }
        __syncthreads();   // protect LDS reuse if a second m0 iteration exists
    }
}

// ---------------- finalize: int fixed-point -> float, + bias ----------------

__global__ void finalize_kernel(int* __restrict__ io, const int* __restrict__ t,
                                const float* __restrict__ bias) {
    int id = blockIdx.x * 256 + threadIdx.x;     // id < NB*NC
    int oi = id / NC;
    int c  = id - oi * NC;
    float v = (float)io[id] * INV_SCALE + bias[t[oi] * NC + c];
    ((float*)io)[id] = v;
}

// ---------------- launch ----------------

extern "C" void kernel_launch(void* const* d_in, const int* in_sizes, int n_in,
                              void* d_out, int out_size, void* d_ws, size_t ws_size,
                              hipStream_t stream) {
    const float* x    = (const float*)d_in[0];
    const int*   t    = (const int*)d_in[1];
    const float* W    = (const float*)d_in[2];
    const float* bias = (const float*)d_in[3];

    int* wsi      = (int*)d_ws;
    int* counts   = wsi;        // 20 ints
    int* offsets  = wsi + 32;   // 21 ints
    int* cursors  = wsi + 64;   // 20 ints
    int* idx_list = wsi + 96;   // NB ints

    hipMemsetAsync(counts, 0, 32 * sizeof(int), stream);
    hipMemsetAsync(d_out, 0, (size_t)NB * NC * sizeof(int), stream);
    count_kernel   <<<NB / 256, 256, 0, stream>>>(t, counts);
    scan_kernel    <<<1, 64, 0, stream>>>(counts, offsets, cursors);
    scatter_kernel <<<NB / 256, 256, 0, stream>>>(t, cursors, idx_list);
    gemm_kernel    <<<NT * MTILES * SPLIT, 256, 0, stream>>>(x, W, offsets, idx_list,
                                                             (int*)d_out);
    finalize_kernel<<<NB * NC / 256, 256, 0, stream>>>((int*)d_out, t, bias);
}

// Round 4
// 75.079 us; speedup vs baseline: 1.8488x; 1.1024x over previous
//
#include <hip/hip_runtime.h>
#include <hip/hip_bf16.h>

#define NB 16384
#define ND 1024
#define NT 20
#define NC 100

#define TILE_M 64
#define KS 64                  // K per staged step
#define SPLIT 2                // each block covers K = 512
#define STEPS 8                // 512 / 64
#define MTILES 16
#define A_TILE_B 16384         // 64 rows x 64 f32 x 4B
#define B_TILE_B 16384         // 128 rows x 64 bf16 x 2B

#define SCALE 4194304.0f       // 2^22 fixed-point (deterministic atomic combine)
#define INV_SCALE (1.0f / 4194304.0f)

typedef __bf16  bf16x8 __attribute__((ext_vector_type(8)));
typedef float   f32x4  __attribute__((ext_vector_type(4)));
typedef unsigned short ushort_t;

__device__ __forceinline__ unsigned int f2bf(float f) {
    unsigned int u = __builtin_bit_cast(unsigned int, f);
    u += 0x7FFFu + ((u >> 16) & 1u);   // RNE
    return u >> 16;
}
__device__ __forceinline__ unsigned long long pack4(float a, float b, float c, float d) {
    return (unsigned long long)f2bf(a)
         | ((unsigned long long)f2bf(b) << 16)
         | ((unsigned long long)f2bf(c) << 32)
         | ((unsigned long long)f2bf(d) << 48);
}
__device__ __forceinline__ bf16x8 mk_frag(float4 a, float4 b) {
    union { unsigned long long u[2]; bf16x8 v; } r;
    r.u[0] = pack4(a.x, a.y, a.z, a.w);
    r.u[1] = pack4(b.x, b.y, b.z, b.w);
    return r.v;
}

// async 16B/lane global->LDS copy; LDS dest is wave-uniform base (+lane*16 by HW)
__device__ __forceinline__ void async_cp16(const void* g, void* l) {
    auto gp = reinterpret_cast<const __attribute__((address_space(1))) unsigned int*>(
        reinterpret_cast<unsigned long long>(g));
    auto lp = reinterpret_cast<__attribute__((address_space(3))) unsigned int*>(
        static_cast<unsigned int>(reinterpret_cast<unsigned long long>(l)));
    __builtin_amdgcn_global_load_lds(gp, lp, 16, 0, 0);
}

// ---------------- bucketing ----------------

__global__ void count_kernel(const int* __restrict__ t, int* __restrict__ counts) {
    __shared__ int h[NT];
    int tid = threadIdx.x;
    if (tid < NT) h[tid] = 0;
    __syncthreads();
    int i = blockIdx.x * 256 + tid;
    atomicAdd(&h[t[i]], 1);
    __syncthreads();
    if (tid < NT && h[tid] > 0) atomicAdd(&counts[tid], h[tid]);
}

__global__ void scan_kernel(const int* __restrict__ counts,
                            int* __restrict__ offsets, int* __restrict__ cursors) {
    if (threadIdx.x == 0) {
        int acc = 0;
        for (int i = 0; i < NT; ++i) {
            offsets[i] = acc; cursors[i] = acc; acc += counts[i];
        }
        offsets[NT] = acc;
    }
}

__global__ void scatter_kernel(const int* __restrict__ t, int* __restrict__ cursors,
                               int* __restrict__ idx_list) {
    __shared__ int h[NT];
    __shared__ int base[NT];
    int tid = threadIdx.x;
    if (tid < NT) h[tid] = 0;
    __syncthreads();
    int i = blockIdx.x * 256 + tid;
    int task = t[i];
    int lpos = atomicAdd(&h[task], 1);
    __syncthreads();
    if (tid < NT && h[tid] > 0) base[tid] = atomicAdd(&cursors[tid], h[tid]);
    __syncthreads();
    idx_list[base[task] + lpos] = i;
}

// ---------------- W f32 -> bf16 pre-convert ----------------

__global__ void wcvt_kernel(const float* __restrict__ W, ushort_t* __restrict__ Wbf) {
    int i = blockIdx.x * 256 + threadIdx.x;          // 8 elems/thread
    const float4* p = (const float4*)(W + (size_t)i * 8);
    float4 a = p[0], b = p[1];
    unsigned long long u0 = pack4(a.x, a.y, a.z, a.w);
    unsigned long long u1 = pack4(b.x, b.y, b.z, b.w);
    uint4 o;
    o.x = (unsigned)u0; o.y = (unsigned)(u0 >> 32);
    o.z = (unsigned)u1; o.w = (unsigned)(u1 >> 32);
    ((uint4*)Wbf)[i] = o;
}

// ---------------- grouped GEMM: async-staged, split-K ----------------
// Block (task, tile, kq): 64 rows x 112 cols x K=512.
// A: f32 tile 64x64 in LDS (global_load_lds, swizzled via source), convert at read.
// B: bf16 tile 128x64 in LDS (global_load_lds of pre-converted Wbf).
// 2-deep double-buffered, counted vmcnt(8), raw barriers.

__global__ __launch_bounds__(256, 2) void gemm_kernel(
    const float* __restrict__ x, const ushort_t* __restrict__ Wbf,
    const int* __restrict__ offsets, const int* __restrict__ idx_list,
    int* __restrict__ outi)
{
    __shared__ __align__(16) char lds[2 * A_TILE_B + 2 * B_TILE_B];   // A0 A1 B0 B1
    const int bid  = blockIdx.x;
    const int task = bid >> 5;                  // MTILES*SPLIT = 32
    const int rem  = bid & 31;
    const int kq   = rem >> 4;                  // 0..1
    const int tile = rem & 15;
    const int seg  = offsets[task];
    const int cnt  = offsets[task + 1] - seg;
    const int kbase = kq * (ND / SPLIT);        // 0 or 512
    if (tile * TILE_M >= cnt) return;

    const int tid   = threadIdx.x;
    const int wave  = tid >> 6;
    const int lane  = tid & 63;
    const int rsel  = lane & 15;
    const int khalf = lane >> 4;

    // ---- staging source descriptors (per lane, 4 insts each for A and B) ----
    int aRow[4], aOffF[4];
#pragma unroll
    for (int jj = 0; jj < 4; ++jj) {
        int j    = 4 * wave + jj;
        int row  = j * 4 + (lane >> 4);         // 0..63
        int byte = (lane & 15) * 16;            // 0..240
        int logb = byte ^ ((row & 7) << 4);     // inverse-swizzled source byte
        aRow[jj]  = row;
        aOffF[jj] = logb >> 2;                  // f32 index within K-window
    }
    const ushort_t* srcB[4];
#pragma unroll
    for (int jj = 0; jj < 4; ++jj) {
        int j    = 4 * wave + jj;
        int c    = j * 8 + (lane >> 3);         // 0..127
        int byte = (lane & 7) * 16;             // 0..112
        int logb = byte ^ ((c & 7) << 4);
        int creal = (c < NC) ? c : 0;           // pad rows: garbage, discarded
        srcB[jj] = Wbf + ((size_t)task * NC + creal) * ND + kbase + (logb >> 1);
    }

    const int rowA = wave * 16 + rsel;
    const int swzA = (rowA & 7) << 4;
    f32x4 acc[7];

    for (int m0 = tile * TILE_M; m0 < cnt; m0 += MTILES * TILE_M) {
        const float* srcA[4];
#pragma unroll
        for (int jj = 0; jj < 4; ++jj) {
            int sr = m0 + aRow[jj];
            srcA[jj] = x + (size_t)idx_list[seg + (sr < cnt ? sr : 0)] * ND
                         + kbase + aOffF[jj];
        }
#pragma unroll
        for (int n = 0; n < 7; ++n) acc[n] = (f32x4){0.f, 0.f, 0.f, 0.f};

        auto STAGE = [&](int s) {
            char* Ad = lds + (s & 1) * A_TILE_B;
            char* Bd = lds + 2 * A_TILE_B + (s & 1) * B_TILE_B;
#pragma unroll
            for (int jj = 0; jj < 4; ++jj)
                async_cp16(srcA[jj] + s * KS, Ad + (4 * wave + jj) * 1024);
#pragma unroll
            for (int jj = 0; jj < 4; ++jj)
                async_cp16(srcB[jj] + s * KS, Bd + (4 * wave + jj) * 1024);
        };
        auto COMPUTE = [&](int s) {
            const char* Ab = lds + (s & 1) * A_TILE_B;
            const char* Bb = lds + 2 * A_TILE_B + (s & 1) * B_TILE_B;
#pragma unroll
            for (int kk = 0; kk < 2; ++kk) {
                int abase = kk * 128 + khalf * 32;
                float4 a0 = *(const float4*)(Ab + rowA * 256 + ((abase)      ^ swzA));
                float4 a1 = *(const float4*)(Ab + rowA * 256 + ((abase + 16) ^ swzA));
                bf16x8 af = mk_frag(a0, a1);
#pragma unroll
                for (int n = 0; n < 7; ++n) {
                    int c = n * 16 + rsel;
                    bf16x8 bf = *(const bf16x8*)(Bb + c * 128 +
                                   ((kk * 64 + khalf * 16) ^ ((c & 7) << 4)));
                    acc[n] = __builtin_amdgcn_mfma_f32_16x16x32_bf16(af, bf, acc[n], 0, 0, 0);
                }
            }
        };

        // make sure prior users of the LDS buffers are done (multi-m0 case)
        asm volatile("s_waitcnt lgkmcnt(0)" ::: "memory");
        __builtin_amdgcn_s_barrier();

        STAGE(0);
        STAGE(1);
        asm volatile("s_waitcnt vmcnt(8)" ::: "memory");   // S(0) landed
        __builtin_amdgcn_sched_barrier(0);
        __builtin_amdgcn_s_barrier();

#pragma unroll
        for (int s = 0; s < STEPS; ++s) {
            COMPUTE(s);
            if (s == STEPS - 1) break;
            asm volatile("s_waitcnt lgkmcnt(0)" ::: "memory");   // my reads done
            __builtin_amdgcn_s_barrier();                        // all reads done
            if (s < STEPS - 2) {
                STAGE(s + 2);                                    // overwrite buf s&1
                asm volatile("s_waitcnt vmcnt(8)" ::: "memory"); // S(s+1) landed
            } else {
                asm volatile("s_waitcnt vmcnt(0)" ::: "memory"); // S(7) landed
            }
            __builtin_amdgcn_sched_barrier(0);
            __builtin_amdgcn_s_barrier();
        }

        // epilogue: fixed-point atomic accumulate (order-independent)
        const int rgrp = (lane >> 4) * 4;
#pragma unroll
        for (int n = 0; n < 7; ++n) {
            int c = n * 16 + rsel;
            if (c < NC) {
#pragma unroll
                for (int r = 0; r < 4; ++r) {
                    int gm = m0 + wave * 16 + rgrp + r;
                    if (gm < cnt) {
                        int oi = idx_list[seg + gm];
                        atomicAdd(&outi[(size_t)oi * NC + c],
                                  __float2int_rn(acc[n][r] * SCALE));
                    }
                }
            }
        }
        asm volatile("s_waitcnt vmcnt(0)" ::: "memory");   // drain atomics (vmcnt bookkeeping)
    }
}

// ---------------- finalize: fixed-point -> float, + bias ----------------

__global__ void finalize_kernel(int* __restrict__ io, const int* __restrict__ t,
                                const float* __restrict__ bias) {
    int id = blockIdx.x * 256 + threadIdx.x;     // NB*NC/2 threads
    int2 v = ((const int2*)io)[id];
    int e0 = 2 * id;
    int oi = e0 / NC;
    int c  = e0 - oi * NC;                        // even, c+1 <= 99
    const float* brow = bias + t[oi] * NC;
    float2 o;
    o.x = (float)v.x * INV_SCALE + brow[c];
    o.y = (float)v.y * INV_SCALE + brow[c + 1];
    ((float2*)io)[id] = o;
}

// ---------------- launch ----------------

extern "C" void kernel_launch(void* const* d_in, const int* in_sizes, int n_in,
                              void* d_out, int out_size, void* d_ws, size_t ws_size,
                              hipStream_t stream) {
    const float* x    = (const float*)d_in[0];
    const int*   t    = (const int*)d_in[1];
    const float* W    = (const float*)d_in[2];
    const float* bias = (const float*)d_in[3];

    int* wsi      = (int*)d_ws;
    int* counts   = wsi;            // 32 ints
    int* offsets  = wsi + 32;       // 21 ints
    int* cursors  = wsi + 64;       // 20 ints
    int* idx_list = wsi + 96;       // NB ints
    ushort_t* Wbf = (ushort_t*)(wsi + 16512);   // byte offset 66048, 4.10 MB

    hipMemsetAsync(counts, 0, 32 * sizeof(int), stream);
    hipMemsetAsync(d_out, 0, (size_t)NB * NC * sizeof(int), stream);
    wcvt_kernel    <<<NT * NC * ND / (256 * 8), 256, 0, stream>>>(W, Wbf);   // 1000 blocks
    count_kernel   <<<NB / 256, 256, 0, stream>>>(t, counts);
    scan_kernel    <<<1, 64, 0, stream>>>(counts, offsets, cursors);
    scatter_kernel <<<NB / 256, 256, 0, stream>>>(t, cursors, idx_list);
    gemm_kernel    <<<NT * MTILES * SPLIT, 256, 0, stream>>>(x, Wbf, offsets, idx_list,
                                                             (int*)d_out);
    finalize_kernel<<<NB * NC / 512, 256, 0, stream>>>((int*)d_out, t, bias);
}

// Round 5
// 75.048 us; speedup vs baseline: 1.8496x; 1.0004x over previous
//
#include <hip/hip_runtime.h>
#include <hip/hip_bf16.h>

#define NB 16384
#define ND 1024
#define NT 20
#define NC 100

#define SPLIT 2                 // K split: each wave does K=512
#define KW (ND / SPLIT)         // 512
#define KSTEPS (KW / 32)        // 16 MFMA k-steps
#define SLOTS 56                // 16-row tile slots per (task, kq); stride loop covers overflow
#define WAVES_TOTAL (NT * SLOTS * SPLIT)   // 2240
#define GRID_BLOCKS (WAVES_TOTAL / 4)      // 560

typedef __bf16  bf16x8 __attribute__((ext_vector_type(8)));
typedef float   f32x4  __attribute__((ext_vector_type(4)));
typedef unsigned short ushort_t;

__device__ __forceinline__ unsigned int f2bf(float f) {
    unsigned int u = __builtin_bit_cast(unsigned int, f);
    u += 0x7FFFu + ((u >> 16) & 1u);   // RNE
    return u >> 16;
}
__device__ __forceinline__ unsigned long long pack4(float a, float b, float c, float d) {
    return (unsigned long long)f2bf(a)
         | ((unsigned long long)f2bf(b) << 16)
         | ((unsigned long long)f2bf(c) << 32)
         | ((unsigned long long)f2bf(d) << 48);
}
__device__ __forceinline__ bf16x8 mk_frag(float4 a, float4 b) {
    union { unsigned long long u[2]; bf16x8 v; } r;
    r.u[0] = pack4(a.x, a.y, a.z, a.w);
    r.u[1] = pack4(b.x, b.y, b.z, b.w);
    return r.v;
}

// ---------------- bucketing ----------------

__global__ void count_kernel(const int* __restrict__ t, int* __restrict__ counts) {
    __shared__ int h[NT];
    int tid = threadIdx.x;
    if (tid < NT) h[tid] = 0;
    __syncthreads();
    int i = blockIdx.x * 256 + tid;
    atomicAdd(&h[t[i]], 1);
    __syncthreads();
    if (tid < NT && h[tid] > 0) atomicAdd(&counts[tid], h[tid]);
}

__global__ void scan_kernel(const int* __restrict__ counts,
                            int* __restrict__ offsets, int* __restrict__ cursors) {
    if (threadIdx.x == 0) {
        int acc = 0;
        for (int i = 0; i < NT; ++i) {
            offsets[i] = acc; cursors[i] = acc; acc += counts[i];
        }
        offsets[NT] = acc;
    }
}

__global__ void scatter_kernel(const int* __restrict__ t, int* __restrict__ cursors,
                               int* __restrict__ idx_list) {
    __shared__ int h[NT];
    __shared__ int base[NT];
    int tid = threadIdx.x;
    if (tid < NT) h[tid] = 0;
    __syncthreads();
    int i = blockIdx.x * 256 + tid;
    int task = t[i];
    int lpos = atomicAdd(&h[task], 1);
    __syncthreads();
    if (tid < NT && h[tid] > 0) base[tid] = atomicAdd(&cursors[tid], h[tid]);
    __syncthreads();
    idx_list[base[task] + lpos] = i;
}

// ---------------- W f32 -> bf16 pre-convert ----------------

__global__ void wcvt_kernel(const float* __restrict__ W, ushort_t* __restrict__ Wbf) {
    int i = blockIdx.x * 256 + threadIdx.x;          // 8 elems/thread
    const float4* p = (const float4*)(W + (size_t)i * 8);
    float4 a = p[0], b = p[1];
    unsigned long long u0 = pack4(a.x, a.y, a.z, a.w);
    unsigned long long u1 = pack4(b.x, b.y, b.z, b.w);
    uint4 o;
    o.x = (unsigned)u0; o.y = (unsigned)(u0 >> 32);
    o.z = (unsigned)u1; o.w = (unsigned)(u1 >> 32);
    ((uint4*)Wbf)[i] = o;
}

// ---------------- grouped GEMM: wave-independent, barrier-free, LDS-free ----
// Each wave: 16 rows x 112 cols x K=512. A f32 global->reg (k-contiguous),
// convert in-reg; B bf16 global->reg (L2-hot). kq=0 -> out0 (d_out),
// kq=1 -> out1 (ws partial). Deterministic: each element written once per buf.

__global__ __launch_bounds__(256, 4) void gemm_kernel(
    const float* __restrict__ x, const ushort_t* __restrict__ Wbf,
    const int* __restrict__ offsets, const int* __restrict__ idx_list,
    float* __restrict__ out0, float* __restrict__ out1)
{
    const int w    = blockIdx.x * 4 + (threadIdx.x >> 6);
    const int task = w / (SLOTS * SPLIT);
    const int r    = w - task * (SLOTS * SPLIT);
    const int kq   = r / SLOTS;
    const int tile = r - kq * SLOTS;
    const int lane = threadIdx.x & 63;
    const int csel = lane & 15;            // A row within tile / B col within frag / C col
    const int kb   = (lane >> 4) * 8;      // k offset within 32-block

    const int seg = offsets[task];
    const int cnt = offsets[task + 1] - seg;
    const int kbase = kq * KW;

    // B fragment pointers: col c = n*16 + csel (clamped), k slice starts at kb
    const ushort_t* bp[7];
#pragma unroll
    for (int n = 0; n < 7; ++n) {
        int c = n * 16 + csel;
        if (c >= NC) c = NC - 1;           // pad cols read a valid row; discarded at store
        bp[n] = Wbf + ((size_t)task * NC + c) * ND + kbase + kb;
    }
    float* __restrict__ outP = kq ? out1 : out0;

    for (int m0 = tile * 16; m0 < cnt; m0 += SLOTS * 16) {
        int mr = m0 + csel;
        int arow = idx_list[seg + (mr < cnt ? mr : cnt - 1)];
        const float* pa = x + (size_t)arow * ND + kbase + kb;

        f32x4 acc[7];
#pragma unroll
        for (int n = 0; n < 7; ++n) acc[n] = (f32x4){0.f, 0.f, 0.f, 0.f};

#pragma unroll 4
        for (int kk = 0; kk < KSTEPS; ++kk) {
            float4 a0 = *(const float4*)(pa + kk * 32);
            float4 a1 = *(const float4*)(pa + kk * 32 + 4);
            bf16x8 af = mk_frag(a0, a1);
#pragma unroll
            for (int n = 0; n < 7; ++n) {
                bf16x8 bf = *(const bf16x8*)(bp[n] + kk * 32);
                acc[n] = __builtin_amdgcn_mfma_f32_16x16x32_bf16(af, bf, acc[n], 0, 0, 0);
            }
        }

        // store: C/D frag col = csel, row = (lane>>4)*4 + reg
        int oi[4];
#pragma unroll
        for (int rr = 0; rr < 4; ++rr) {
            int gm = m0 + (lane >> 4) * 4 + rr;
            oi[rr] = (gm < cnt) ? idx_list[seg + gm] : -1;
        }
#pragma unroll
        for (int n = 0; n < 7; ++n) {
            int c = n * 16 + csel;
            if (c < NC) {
#pragma unroll
                for (int rr = 0; rr < 4; ++rr)
                    if (oi[rr] >= 0)
                        outP[(size_t)oi[rr] * NC + c] = acc[n][rr];
            }
        }
    }
}

// ---------------- finalize: out = p0 + p1 + bias ----------------

__global__ void finalize_kernel(float* __restrict__ o0, const float* __restrict__ o1,
                                const int* __restrict__ t, const float* __restrict__ bias) {
    int id = blockIdx.x * 256 + threadIdx.x;     // NB*NC/2 threads, float2 each
    float2 v0 = ((const float2*)o0)[id];
    float2 v1 = ((const float2*)o1)[id];
    int e0 = 2 * id;
    int oi = e0 / NC;
    int c  = e0 - oi * NC;                        // even, c+1 <= 99
    const float* brow = bias + t[oi] * NC;
    float2 o;
    o.x = v0.x + v1.x + brow[c];
    o.y = v0.y + v1.y + brow[c + 1];
    ((float2*)o0)[id] = o;
}

// ---------------- launch ----------------

extern "C" void kernel_launch(void* const* d_in, const int* in_sizes, int n_in,
                              void* d_out, int out_size, void* d_ws, size_t ws_size,
                              hipStream_t stream) {
    const float* x    = (const float*)d_in[0];
    const int*   t    = (const int*)d_in[1];
    const float* W    = (const float*)d_in[2];
    const float* bias = (const float*)d_in[3];

    char* ws = (char*)d_ws;
    int* counts   = (int*)ws;                    // 32 ints
    int* offsets  = (int*)(ws + 128);            // 21 ints
    int* cursors  = (int*)(ws + 256);            // 20 ints
    int* idx_list = (int*)(ws + 384);            // NB ints -> ends at 65920
    ushort_t* Wbf = (ushort_t*)(ws + 69632);     // 4,096,000 B
    float* out1   = (float*)(ws + 69632 + (size_t)NT * NC * ND * 2);  // 6,553,600 B

    hipMemsetAsync(counts, 0, 32 * sizeof(int), stream);
    wcvt_kernel    <<<NT * NC * ND / (256 * 8), 256, 0, stream>>>(W, Wbf);
    count_kernel   <<<NB / 256, 256, 0, stream>>>(t, counts);
    scan_kernel    <<<1, 64, 0, stream>>>(counts, offsets, cursors);
    scatter_kernel <<<NB / 256, 256, 0, stream>>>(t, cursors, idx_list);
    gemm_kernel    <<<GRID_BLOCKS, 256, 0, stream>>>(x, Wbf, offsets, idx_list,
                                                     (float*)d_out, out1);
    finalize_kernel<<<NB * NC / 512, 256, 0, stream>>>((float*)d_out, out1, t, bias);
}